// Round 1
// baseline (2849.850 us; speedup 1.0000x reference)
//
#include <hip/hip_runtime.h>
#include <hip/hip_bf16.h>

#define CDIM 32
#define KCLS 20
#define NBASE 12
#define PPROP 1024
#define TBLW 20   // 18 sem cols (2..19) + binary + count

__device__ __forceinline__ void lds_addf(float* p, float v) {
  __hip_atomic_fetch_add(p, v, __ATOMIC_RELAXED, __HIP_MEMORY_SCOPE_WORKGROUP);
}
__device__ __forceinline__ void glb_addf(float* p, float v) {
  __hip_atomic_fetch_add(p, v, __ATOMIC_RELAXED, __HIP_MEMORY_SCOPE_AGENT);
}

// ---------------- scores: open-vocab renormalized softmax-gate ----------------
__global__ void k_scores(const float* __restrict__ sem, const float* __restrict__ bin,
                         float* __restrict__ out, int n) {
  int stride = gridDim.x * blockDim.x;
  for (int i = blockIdx.x * blockDim.x + threadIdx.x; i < n; i += stride) {
    const float4* r = reinterpret_cast<const float4*>(sem + (size_t)i * KCLS);
    float s[KCLS];
    float4 v;
    v = r[0]; s[0]=v.x; s[1]=v.y; s[2]=v.z; s[3]=v.w;
    v = r[1]; s[4]=v.x; s[5]=v.y; s[6]=v.z; s[7]=v.w;
    v = r[2]; s[8]=v.x; s[9]=v.y; s[10]=v.z; s[11]=v.w;
    v = r[3]; s[12]=v.x; s[13]=v.y; s[14]=v.z; s[15]=v.w;
    v = r[4]; s[16]=v.x; s[17]=v.y; s[18]=v.z; s[19]=v.w;

    float m12 = s[0];
#pragma unroll
    for (int k = 1; k < NBASE; k++) m12 = fmaxf(m12, s[k]);
    float sum12 = 0.f;
#pragma unroll
    for (int k = 0; k < NBASE; k++) { s[k] = __expf(s[k] - m12); sum12 += s[k]; }

    float m8 = s[NBASE];
#pragma unroll
    for (int k = NBASE + 1; k < KCLS; k++) m8 = fmaxf(m8, s[k]);
    float sum8 = 0.f;
#pragma unroll
    for (int k = NBASE; k < KCLS; k++) { s[k] = __expf(s[k] - m8); sum8 += s[k]; }

    float sig = 1.f / (1.f + __expf(-bin[i]));
    // analytic: sum(scores_pre) == sig*1 + (1-sig)*1 == 1, fold gate/softmax-denoms
    float cb = sig / sum12;
    float cn = (1.f - sig) / sum8;
#pragma unroll
    for (int k = 0; k < NBASE; k++) s[k] *= cb;
#pragma unroll
    for (int k = NBASE; k < KCLS; k++) s[k] *= cn;

    float4* o = reinterpret_cast<float4*>(out + (size_t)i * KCLS);
    o[0] = make_float4(s[0], s[1], s[2], s[3]);
    o[1] = make_float4(s[4], s[5], s[6], s[7]);
    o[2] = make_float4(s[8], s[9], s[10], s[11]);
    o[3] = make_float4(s[12], s[13], s[14], s[15]);
    o[4] = make_float4(s[16], s[17], s[18], s[19]);
  }
}

// ---------------- proposal scatter-mean accumulation ----------------
__global__ __launch_bounds__(512) void k_scatter(const float* __restrict__ sem,
    const float* __restrict__ bin, const int* __restrict__ pidx,
    const int* __restrict__ pid, float* __restrict__ acc, int m) {
  __shared__ float tbl[PPROP * TBLW];  // 80 KiB
  for (int t = threadIdx.x; t < PPROP * TBLW; t += blockDim.x) tbl[t] = 0.f;
  __syncthreads();

  int stride = gridDim.x * blockDim.x;
  for (int i = blockIdx.x * blockDim.x + threadIdx.x; i < m; i += stride) {
    int q = pidx[i];
    int p = pid[i];
    const float* row = sem + (size_t)q * KCLS;
    // channels 2..19 (LABEL_SHIFT=2): float2 @+2 (8B-aligned), float4 @+4,+8,+12,+16
    float2 a  = *reinterpret_cast<const float2*>(row + 2);
    float4 c0 = *reinterpret_cast<const float4*>(row + 4);
    float4 c1 = *reinterpret_cast<const float4*>(row + 8);
    float4 c2 = *reinterpret_cast<const float4*>(row + 12);
    float4 c3 = *reinterpret_cast<const float4*>(row + 16);
    float bv = bin[q];
    float* t = tbl + p * TBLW;
    lds_addf(t + 0, a.x);  lds_addf(t + 1, a.y);
    lds_addf(t + 2, c0.x); lds_addf(t + 3, c0.y); lds_addf(t + 4, c0.z); lds_addf(t + 5, c0.w);
    lds_addf(t + 6, c1.x); lds_addf(t + 7, c1.y); lds_addf(t + 8, c1.z); lds_addf(t + 9, c1.w);
    lds_addf(t +10, c2.x); lds_addf(t +11, c2.y); lds_addf(t +12, c2.z); lds_addf(t +13, c2.w);
    lds_addf(t +14, c3.x); lds_addf(t +15, c3.y); lds_addf(t +16, c3.z); lds_addf(t +17, c3.w);
    lds_addf(t +18, bv);
    lds_addf(t +19, 1.f);
  }
  __syncthreads();
  for (int t = threadIdx.x; t < PPROP * TBLW; t += blockDim.x) {
    float v = tbl[t];
    if (v != 0.f) glb_addf(acc + t, v);
  }
}

// ---------------- mask/iou heads + BN statistics over h1 = feats@W1+b1 ----------------
__global__ void k_heads(const float* __restrict__ feats,
    const float* __restrict__ W1,  const float* __restrict__ b1,
    const float* __restrict__ Wm1, const float* __restrict__ bm1,
    const float* __restrict__ Wm2, const float* __restrict__ bm2,
    const float* __restrict__ Wi,  const float* __restrict__ bi,
    float* __restrict__ mask_out, float* __restrict__ iou_out,
    float* __restrict__ stats, int n) {
  float hs[CDIM], hq[CDIM];
#pragma unroll
  for (int j = 0; j < CDIM; j++) { hs[j] = 0.f; hq[j] = 0.f; }

  int stride = gridDim.x * blockDim.x;
  for (int i = blockIdx.x * blockDim.x + threadIdx.x; i < n; i += stride) {
    float f[CDIM];
    const float4* fr = reinterpret_cast<const float4*>(feats + (size_t)i * CDIM);
#pragma unroll
    for (int t = 0; t < 8; t++) {
      float4 v = fr[t];
      f[4*t] = v.x; f[4*t+1] = v.y; f[4*t+2] = v.z; f[4*t+3] = v.w;
    }
    // mask head hidden: relu(f @ Wm1 + bm1) . Wm2 + bm2
    float a[CDIM];
#pragma unroll
    for (int j = 0; j < CDIM; j++) a[j] = bm1[j];
#pragma unroll
    for (int c = 0; c < CDIM; c++) {
      float fc = f[c];
#pragma unroll
      for (int j = 0; j < CDIM; j++) a[j] = fmaf(fc, Wm1[c * CDIM + j], a[j]);
    }
    float mk = bm2[0];
#pragma unroll
    for (int j = 0; j < CDIM; j++) mk = fmaf(fmaxf(a[j], 0.f), Wm2[j], mk);
    mask_out[i] = mk;

    float io = bi[0];
#pragma unroll
    for (int c = 0; c < CDIM; c++) io = fmaf(f[c], Wi[c], io);
    iou_out[i] = io;

    // h1 = f @ W1 + b1 for BN stats (reuse a)
#pragma unroll
    for (int j = 0; j < CDIM; j++) a[j] = b1[j];
#pragma unroll
    for (int c = 0; c < CDIM; c++) {
      float fc = f[c];
#pragma unroll
      for (int j = 0; j < CDIM; j++) a[j] = fmaf(fc, W1[c * CDIM + j], a[j]);
    }
#pragma unroll
    for (int j = 0; j < CDIM; j++) { hs[j] += a[j]; hq[j] = fmaf(a[j], a[j], hq[j]); }
  }

  __shared__ float red[2 * CDIM];
  for (int t = threadIdx.x; t < 2 * CDIM; t += blockDim.x) red[t] = 0.f;
  __syncthreads();
#pragma unroll
  for (int j = 0; j < CDIM; j++) { lds_addf(&red[j], hs[j]); lds_addf(&red[CDIM + j], hq[j]); }
  __syncthreads();
  for (int t = threadIdx.x; t < 2 * CDIM; t += blockDim.x) glb_addf(&stats[t], red[t]);
}

// ---------------- pt_offsets: Linear->BN(trained stats)->ReLU->Linear ----------------
__global__ void k_offsets(const float* __restrict__ feats,
    const float* __restrict__ W1, const float* __restrict__ b1,
    const float* __restrict__ g1, const float* __restrict__ be1,
    const float* __restrict__ W2, const float* __restrict__ b2,
    const float* __restrict__ stats, float* __restrict__ out_off,
    int n, float invN) {
  float sc[CDIM], tc[CDIM];
#pragma unroll
  for (int j = 0; j < CDIM; j++) {
    float mu  = stats[j] * invN;
    float var = stats[CDIM + j] * invN - mu * mu;
    float isd = rsqrtf(var + 1e-4f);
    sc[j] = g1[j] * isd;
    tc[j] = be1[j] - mu * sc[j];
  }
  float w2x[CDIM], w2y[CDIM], w2z[CDIM];
#pragma unroll
  for (int j = 0; j < CDIM; j++) { w2x[j] = W2[j*3]; w2y[j] = W2[j*3+1]; w2z[j] = W2[j*3+2]; }

  int stride = gridDim.x * blockDim.x;
  for (int i = blockIdx.x * blockDim.x + threadIdx.x; i < n; i += stride) {
    float f[CDIM];
    const float4* fr = reinterpret_cast<const float4*>(feats + (size_t)i * CDIM);
#pragma unroll
    for (int t = 0; t < 8; t++) {
      float4 v = fr[t];
      f[4*t] = v.x; f[4*t+1] = v.y; f[4*t+2] = v.z; f[4*t+3] = v.w;
    }
    float a[CDIM];
#pragma unroll
    for (int j = 0; j < CDIM; j++) a[j] = b1[j];
#pragma unroll
    for (int c = 0; c < CDIM; c++) {
      float fc = f[c];
#pragma unroll
      for (int j = 0; j < CDIM; j++) a[j] = fmaf(fc, W1[c * CDIM + j], a[j]);
    }
    float ox = b2[0], oy = b2[1], oz = b2[2];
#pragma unroll
    for (int j = 0; j < CDIM; j++) {
      float y = fmaxf(fmaf(a[j], sc[j], tc[j]), 0.f);
      ox = fmaf(y, w2x[j], ox);
      oy = fmaf(y, w2y[j], oy);
      oz = fmaf(y, w2z[j], oz);
    }
    size_t o = (size_t)i * 3;
    out_off[o] = ox; out_off[o + 1] = oy; out_off[o + 2] = oz;
  }
}

// ---------------- finalize proposal means ----------------
__global__ void k_finalize(const float* __restrict__ acc,
                           float* __restrict__ psem, float* __restrict__ pbin) {
  int p = blockIdx.x * blockDim.x + threadIdx.x;
  if (p < PPROP) {
    const float* t = acc + p * TBLW;
    float cnt = fmaxf(t[19], 1.f);
    float r = 1.f / cnt;
#pragma unroll
    for (int c = 0; c < 18; c++) psem[p * 18 + c] = t[c] * r;
    pbin[p] = t[18] * r;
  }
}

extern "C" void kernel_launch(void* const* d_in, const int* in_sizes, int n_in,
                              void* d_out, int out_size, void* d_ws, size_t ws_size,
                              hipStream_t stream) {
  const float* feats = (const float*)d_in[0];
  const float* sem   = (const float*)d_in[1];
  const float* bin   = (const float*)d_in[2];
  const int*   pidx  = (const int*)d_in[3];
  const int*   pid   = (const int*)d_in[4];
  const float* W1  = (const float*)d_in[5];
  const float* b1  = (const float*)d_in[6];
  const float* g1  = (const float*)d_in[7];
  const float* be1 = (const float*)d_in[8];
  const float* W2  = (const float*)d_in[9];
  const float* b2  = (const float*)d_in[10];
  const float* Wm1 = (const float*)d_in[11];
  const float* bm1 = (const float*)d_in[12];
  const float* Wm2 = (const float*)d_in[13];
  const float* bm2 = (const float*)d_in[14];
  const float* Wi  = (const float*)d_in[15];
  const float* bi  = (const float*)d_in[16];

  int n = in_sizes[2];   // binary_scores is (N,1)
  int m = in_sizes[3];   // memberships

  float* out = (float*)d_out;
  float* o_scores = out;
  float* o_off  = out + (size_t)n * KCLS;
  float* o_psem = o_off + (size_t)n * 3;
  float* o_pbin = o_psem + (size_t)PPROP * 18;
  float* o_mask = o_pbin + PPROP;
  float* o_iou  = o_mask + n;

  float* stats = (float*)d_ws;       // 64 floats: sum[32], sumsq[32]
  float* acc   = stats + 2 * CDIM;   // P*TBLW floats

  // zero accumulators every launch (harness does not re-poison between replays)
  hipMemsetAsync(d_ws, 0, (2 * CDIM + PPROP * TBLW) * sizeof(float), stream);

  k_scores  <<<2048, 256, 0, stream>>>(sem, bin, o_scores, n);
  // run scatter right after scores so semantic_scores is L3-resident for the gather
  k_scatter <<<256, 512, 0, stream>>>(sem, bin, pidx, pid, acc, m);
  k_heads   <<<2048, 256, 0, stream>>>(feats, W1, b1, Wm1, bm1, Wm2, bm2, Wi, bi,
                                       o_mask, o_iou, stats, n);
  k_offsets <<<2048, 256, 0, stream>>>(feats, W1, b1, g1, be1, W2, b2, stats,
                                       o_off, n, 1.0f / (float)n);
  k_finalize<<<4, 256, 0, stream>>>(acc, o_psem, o_pbin);
}

// Round 2
// 1891.287 us; speedup vs baseline: 1.5068x; 1.5068x over previous
//
#include <hip/hip_runtime.h>
#include <hip/hip_bf16.h>

#define CDIM 32
#define KCLS 20
#define NBASE 12
#define PPROP 1024
#define TBLW 20   // 18 sem cols (2..19) + binary + count

__device__ __forceinline__ void lds_addf(float* p, float v) {
  __hip_atomic_fetch_add(p, v, __ATOMIC_RELAXED, __HIP_MEMORY_SCOPE_WORKGROUP);
}
__device__ __forceinline__ void glb_addf(float* p, float v) {
  __hip_atomic_fetch_add(p, v, __ATOMIC_RELAXED, __HIP_MEMORY_SCOPE_AGENT);
}

// ---------------- scores: open-vocab renormalized softmax-gate ----------------
__global__ void k_scores(const float* __restrict__ sem, const float* __restrict__ bin,
                         float* __restrict__ out, int n) {
  int stride = gridDim.x * blockDim.x;
  for (int i = blockIdx.x * blockDim.x + threadIdx.x; i < n; i += stride) {
    const float4* r = reinterpret_cast<const float4*>(sem + (size_t)i * KCLS);
    float s[KCLS];
    float4 v;
    v = r[0]; s[0]=v.x; s[1]=v.y; s[2]=v.z; s[3]=v.w;
    v = r[1]; s[4]=v.x; s[5]=v.y; s[6]=v.z; s[7]=v.w;
    v = r[2]; s[8]=v.x; s[9]=v.y; s[10]=v.z; s[11]=v.w;
    v = r[3]; s[12]=v.x; s[13]=v.y; s[14]=v.z; s[15]=v.w;
    v = r[4]; s[16]=v.x; s[17]=v.y; s[18]=v.z; s[19]=v.w;

    float m12 = s[0];
#pragma unroll
    for (int k = 1; k < NBASE; k++) m12 = fmaxf(m12, s[k]);
    float sum12 = 0.f;
#pragma unroll
    for (int k = 0; k < NBASE; k++) { s[k] = __expf(s[k] - m12); sum12 += s[k]; }

    float m8 = s[NBASE];
#pragma unroll
    for (int k = NBASE + 1; k < KCLS; k++) m8 = fmaxf(m8, s[k]);
    float sum8 = 0.f;
#pragma unroll
    for (int k = NBASE; k < KCLS; k++) { s[k] = __expf(s[k] - m8); sum8 += s[k]; }

    float sig = 1.f / (1.f + __expf(-bin[i]));
    // analytic: renormalization denominator == 1, fold gate/softmax-denoms
    float cb = sig / sum12;
    float cn = (1.f - sig) / sum8;
#pragma unroll
    for (int k = 0; k < NBASE; k++) s[k] *= cb;
#pragma unroll
    for (int k = NBASE; k < KCLS; k++) s[k] *= cn;

    float4* o = reinterpret_cast<float4*>(out + (size_t)i * KCLS);
    o[0] = make_float4(s[0], s[1], s[2], s[3]);
    o[1] = make_float4(s[4], s[5], s[6], s[7]);
    o[2] = make_float4(s[8], s[9], s[10], s[11]);
    o[3] = make_float4(s[12], s[13], s[14], s[15]);
    o[4] = make_float4(s[16], s[17], s[18], s[19]);
  }
}

// ---------------- proposal scatter-mean accumulation ----------------
__global__ __launch_bounds__(512) void k_scatter(const float* __restrict__ sem,
    const float* __restrict__ bin, const int* __restrict__ pidx,
    const int* __restrict__ pid, float* __restrict__ acc, int m) {
  __shared__ float tbl[PPROP * TBLW];  // 80 KiB
  for (int t = threadIdx.x; t < PPROP * TBLW; t += blockDim.x) tbl[t] = 0.f;
  __syncthreads();

  int stride = gridDim.x * blockDim.x;
  for (int i = blockIdx.x * blockDim.x + threadIdx.x; i < m; i += stride) {
    int q = pidx[i];
    int p = pid[i];
    const float* row = sem + (size_t)q * KCLS;
    float2 a  = *reinterpret_cast<const float2*>(row + 2);
    float4 c0 = *reinterpret_cast<const float4*>(row + 4);
    float4 c1 = *reinterpret_cast<const float4*>(row + 8);
    float4 c2 = *reinterpret_cast<const float4*>(row + 12);
    float4 c3 = *reinterpret_cast<const float4*>(row + 16);
    float bv = bin[q];
    float* t = tbl + p * TBLW;
    lds_addf(t + 0, a.x);  lds_addf(t + 1, a.y);
    lds_addf(t + 2, c0.x); lds_addf(t + 3, c0.y); lds_addf(t + 4, c0.z); lds_addf(t + 5, c0.w);
    lds_addf(t + 6, c1.x); lds_addf(t + 7, c1.y); lds_addf(t + 8, c1.z); lds_addf(t + 9, c1.w);
    lds_addf(t +10, c2.x); lds_addf(t +11, c2.y); lds_addf(t +12, c2.z); lds_addf(t +13, c2.w);
    lds_addf(t +14, c3.x); lds_addf(t +15, c3.y); lds_addf(t +16, c3.z); lds_addf(t +17, c3.w);
    lds_addf(t +18, bv);
    lds_addf(t +19, 1.f);
  }
  __syncthreads();
  for (int t = threadIdx.x; t < PPROP * TBLW; t += blockDim.x) {
    float v = tbl[t];
    if (v != 0.f) glb_addf(acc + t, v);
  }
}

// ---------------- mask/iou heads + BN statistics over h1 = feats@W1+b1 ----------------
// __launch_bounds__(256,1): allow full 512-VGPR budget so f/a/hs/hq stay in registers
// (round-1 showed VGPR capped at 64 -> ~640 MB scratch spill traffic, 2.3 ms)
__global__ __launch_bounds__(256, 1) void k_heads(const float* __restrict__ feats,
    const float* __restrict__ W1,  const float* __restrict__ b1,
    const float* __restrict__ Wm1, const float* __restrict__ bm1,
    const float* __restrict__ Wm2, const float* __restrict__ bm2,
    const float* __restrict__ Wi,  const float* __restrict__ bi,
    float* __restrict__ mask_out, float* __restrict__ iou_out,
    float* __restrict__ stats, int n) {
  float hs[CDIM], hq[CDIM];
#pragma unroll
  for (int j = 0; j < CDIM; j++) { hs[j] = 0.f; hq[j] = 0.f; }

  int stride = gridDim.x * blockDim.x;
  for (int i = blockIdx.x * blockDim.x + threadIdx.x; i < n; i += stride) {
    float f[CDIM];
    const float4* fr = reinterpret_cast<const float4*>(feats + (size_t)i * CDIM);
#pragma unroll
    for (int t = 0; t < 8; t++) {
      float4 v = fr[t];
      f[4*t] = v.x; f[4*t+1] = v.y; f[4*t+2] = v.z; f[4*t+3] = v.w;
    }
    // mask head hidden: relu(f @ Wm1 + bm1) . Wm2 + bm2
    float a[CDIM];
#pragma unroll
    for (int j = 0; j < CDIM; j++) a[j] = bm1[j];
#pragma unroll
    for (int c = 0; c < CDIM; c++) {
      float fc = f[c];
#pragma unroll
      for (int j = 0; j < CDIM; j++) a[j] = fmaf(fc, Wm1[c * CDIM + j], a[j]);
    }
    float mk = bm2[0];
#pragma unroll
    for (int j = 0; j < CDIM; j++) mk = fmaf(fmaxf(a[j], 0.f), Wm2[j], mk);
    mask_out[i] = mk;

    float io = bi[0];
#pragma unroll
    for (int c = 0; c < CDIM; c++) io = fmaf(f[c], Wi[c], io);
    iou_out[i] = io;

    // h1 = f @ W1 + b1 for BN stats (reuse a)
#pragma unroll
    for (int j = 0; j < CDIM; j++) a[j] = b1[j];
#pragma unroll
    for (int c = 0; c < CDIM; c++) {
      float fc = f[c];
#pragma unroll
      for (int j = 0; j < CDIM; j++) a[j] = fmaf(fc, W1[c * CDIM + j], a[j]);
    }
#pragma unroll
    for (int j = 0; j < CDIM; j++) { hs[j] += a[j]; hq[j] = fmaf(a[j], a[j], hq[j]); }
  }

  __shared__ float red[2 * CDIM];
  for (int t = threadIdx.x; t < 2 * CDIM; t += blockDim.x) red[t] = 0.f;
  __syncthreads();
#pragma unroll
  for (int j = 0; j < CDIM; j++) { lds_addf(&red[j], hs[j]); lds_addf(&red[CDIM + j], hq[j]); }
  __syncthreads();
  for (int t = threadIdx.x; t < 2 * CDIM; t += blockDim.x) glb_addf(&stats[t], red[t]);
}

// ---------------- tiny: fold BN stats into scale/shift ----------------
__global__ void k_bnprep(const float* __restrict__ stats,
                         const float* __restrict__ g1, const float* __restrict__ be1,
                         float* __restrict__ bnsc, float* __restrict__ bntc, float invN) {
  int j = threadIdx.x;
  if (j < CDIM) {
    float mu  = stats[j] * invN;
    float var = stats[CDIM + j] * invN - mu * mu;
    float isd = rsqrtf(var + 1e-4f);
    float sc = g1[j] * isd;
    bnsc[j] = sc;
    bntc[j] = be1[j] - mu * sc;
  }
}

// ---------------- pt_offsets: Linear->BN(precomputed sc/tc)->ReLU->Linear ----------------
// bnsc/bntc/W2 indexed with wave-uniform indices -> s_load, no VGPR preload arrays
__global__ __launch_bounds__(256, 1) void k_offsets(const float* __restrict__ feats,
    const float* __restrict__ W1, const float* __restrict__ b1,
    const float* __restrict__ W2, const float* __restrict__ b2,
    const float* __restrict__ bnsc, const float* __restrict__ bntc,
    float* __restrict__ out_off, int n) {
  int stride = gridDim.x * blockDim.x;
  for (int i = blockIdx.x * blockDim.x + threadIdx.x; i < n; i += stride) {
    float f[CDIM];
    const float4* fr = reinterpret_cast<const float4*>(feats + (size_t)i * CDIM);
#pragma unroll
    for (int t = 0; t < 8; t++) {
      float4 v = fr[t];
      f[4*t] = v.x; f[4*t+1] = v.y; f[4*t+2] = v.z; f[4*t+3] = v.w;
    }
    float a[CDIM];
#pragma unroll
    for (int j = 0; j < CDIM; j++) a[j] = b1[j];
#pragma unroll
    for (int c = 0; c < CDIM; c++) {
      float fc = f[c];
#pragma unroll
      for (int j = 0; j < CDIM; j++) a[j] = fmaf(fc, W1[c * CDIM + j], a[j]);
    }
    float ox = b2[0], oy = b2[1], oz = b2[2];
#pragma unroll
    for (int j = 0; j < CDIM; j++) {
      float y = fmaxf(fmaf(a[j], bnsc[j], bntc[j]), 0.f);
      ox = fmaf(y, W2[j * 3 + 0], ox);
      oy = fmaf(y, W2[j * 3 + 1], oy);
      oz = fmaf(y, W2[j * 3 + 2], oz);
    }
    size_t o = (size_t)i * 3;
    out_off[o] = ox; out_off[o + 1] = oy; out_off[o + 2] = oz;
  }
}

// ---------------- finalize proposal means ----------------
__global__ void k_finalize(const float* __restrict__ acc,
                           float* __restrict__ psem, float* __restrict__ pbin) {
  int p = blockIdx.x * blockDim.x + threadIdx.x;
  if (p < PPROP) {
    const float* t = acc + p * TBLW;
    float cnt = fmaxf(t[19], 1.f);
    float r = 1.f / cnt;
#pragma unroll
    for (int c = 0; c < 18; c++) psem[p * 18 + c] = t[c] * r;
    pbin[p] = t[18] * r;
  }
}

extern "C" void kernel_launch(void* const* d_in, const int* in_sizes, int n_in,
                              void* d_out, int out_size, void* d_ws, size_t ws_size,
                              hipStream_t stream) {
  const float* feats = (const float*)d_in[0];
  const float* sem   = (const float*)d_in[1];
  const float* bin   = (const float*)d_in[2];
  const int*   pidx  = (const int*)d_in[3];
  const int*   pid   = (const int*)d_in[4];
  const float* W1  = (const float*)d_in[5];
  const float* b1  = (const float*)d_in[6];
  const float* g1  = (const float*)d_in[7];
  const float* be1 = (const float*)d_in[8];
  const float* W2  = (const float*)d_in[9];
  const float* b2  = (const float*)d_in[10];
  const float* Wm1 = (const float*)d_in[11];
  const float* bm1 = (const float*)d_in[12];
  const float* Wm2 = (const float*)d_in[13];
  const float* bm2 = (const float*)d_in[14];
  const float* Wi  = (const float*)d_in[15];
  const float* bi  = (const float*)d_in[16];

  int n = in_sizes[2];   // binary_scores is (N,1)
  int m = in_sizes[3];   // memberships

  float* out = (float*)d_out;
  float* o_scores = out;
  float* o_off  = out + (size_t)n * KCLS;
  float* o_psem = o_off + (size_t)n * 3;
  float* o_pbin = o_psem + (size_t)PPROP * 18;
  float* o_mask = o_pbin + PPROP;
  float* o_iou  = o_mask + n;

  float* stats = (float*)d_ws;         // 64 floats: sum[32], sumsq[32]
  float* bnsc  = stats + 2 * CDIM;     // 32
  float* bntc  = bnsc + CDIM;          // 32
  float* acc   = bntc + CDIM;          // P*TBLW floats

  // zero accumulators every launch (harness does not re-poison between replays)
  hipMemsetAsync(d_ws, 0, (4 * CDIM + PPROP * TBLW) * sizeof(float), stream);

  k_scores  <<<2048, 256, 0, stream>>>(sem, bin, o_scores, n);
  // run scatter right after scores so semantic_scores is L3-resident for the gather
  k_scatter <<<256, 512, 0, stream>>>(sem, bin, pidx, pid, acc, m);
  k_heads   <<<2048, 256, 0, stream>>>(feats, W1, b1, Wm1, bm1, Wm2, bm2, Wi, bi,
                                       o_mask, o_iou, stats, n);
  k_bnprep  <<<1, 64, 0, stream>>>(stats, g1, be1, bnsc, bntc, 1.0f / (float)n);
  k_offsets <<<2048, 256, 0, stream>>>(feats, W1, b1, W2, b2, bnsc, bntc, o_off, n);
  k_finalize<<<4, 256, 0, stream>>>(acc, o_psem, o_pbin);
}